// Round 12
// baseline (377.394 us; speedup 1.0000x reference)
//
#include <hip/hip_runtime.h>

// ---------------------------------------------------------------------------
// AlignableCaslAgent forward.  Inputs f32, outputs f32 (verified rounds 4-11).
// Round 11: WAVE-SYNCHRONOUS convs - each wave owns its rows + a private
// double-buffered LDS staging region; block barriers replaced by wave-local
// lgkmcnt(0) waits (global prefetch stays in flight).  Waves slip freely,
// hiding load latency that the __syncthreads convoy could not (m114/m131).
// ---------------------------------------------------------------------------

typedef unsigned short u16;
typedef unsigned int u32;
typedef __attribute__((ext_vector_type(8))) short bf16x8;
typedef __attribute__((ext_vector_type(4))) float f32x4;

__device__ __forceinline__ float b2f(u16 u) {
    union { u32 i; float f; } v; v.i = ((u32)u) << 16; return v.f;
}
__device__ __forceinline__ u16 f2b(float f) {
    union { float f; u32 i; } v; v.f = f;
    u32 r = v.i + 0x7fffu + ((v.i >> 16) & 1u);
    return (u16)(r >> 16);
}
// wave-local LDS sync: fence compiler motion, drain lgkmcnt only
// (0xC07F = vmcnt:max, expcnt:max, lgkmcnt:0 -> global loads stay in flight)
__device__ __forceinline__ void wave_lds_sync() {
    __builtin_amdgcn_wave_barrier();
    __builtin_amdgcn_s_waitcnt(0xC07F);
    __builtin_amdgcn_wave_barrier();
}

// ---------------------------------------------------------------------------
// conv1, wave-synchronous.  x f32 [b][2][84][84], K=64 (k=ky*8+kx), OC=32.
// Each wave stages its own 32 rows into a private LDS region; no barriers.
// ---------------------------------------------------------------------------
__global__ __launch_bounds__(256) void conv1_mfma(
    const float* __restrict__ x, long boff,
    const u16* __restrict__ Wp,
    const float* __restrict__ bias_v, const float* __restrict__ bias_a,
    u16* __restrict__ outp, int Mtot)
{
    __shared__ __attribute__((aligned(16))) u16 As[4 * 2304];   // [wave][32*72]

    const int tid = threadIdx.x;
    const int wave = tid >> 6, lane = tid & 63, quad = lane >> 4, l16 = lane & 15;
    const int t = blockIdx.y;
    const u16* Wpt = Wp + t * 2048;
    const float* bias = t ? bias_a : bias_v;
    u16* outt = outp + (long)t * Mtot * 32;

    const int mbase = blockIdx.x * 128 + wave * 32;
    const int rl = lane >> 1, h = lane & 1;
    int m = mbase + rl; if (m > Mtot - 1) m = Mtot - 1;
    const int bl = m / 400, p = m % 400;
    const int oy = p / 20, ox = p % 20;
    const float* F = x + boff + (long)bl * 14112 + t * 7056
                     + (long)(oy * 4) * 84 + ox * 4;

    {
        u16 tmp[32];
#pragma unroll
        for (int rr = 0; rr < 4; ++rr) {
            const int ky = h * 4 + rr;
            float4 v0 = *(const float4*)(F + ky * 84);
            float4 v1 = *(const float4*)(F + ky * 84 + 4);
            tmp[rr * 8 + 0] = f2b(v0.x); tmp[rr * 8 + 1] = f2b(v0.y);
            tmp[rr * 8 + 2] = f2b(v0.z); tmp[rr * 8 + 3] = f2b(v0.w);
            tmp[rr * 8 + 4] = f2b(v1.x); tmp[rr * 8 + 5] = f2b(v1.y);
            tmp[rr * 8 + 6] = f2b(v1.z); tmp[rr * 8 + 7] = f2b(v1.w);
        }
        u16* dst = As + wave * 2304 + rl * 72 + h * 32;
        const uint4* s = (const uint4*)tmp;
        *(uint4*)(dst)      = s[0];
        *(uint4*)(dst + 8)  = s[1];
        *(uint4*)(dst + 16) = s[2];
        *(uint4*)(dst + 24) = s[3];
    }
    wave_lds_sync();

    const u16* rb = As + wave * 2304;
    f32x4 acc[2][2];
#pragma unroll
    for (int mi = 0; mi < 2; ++mi)
#pragma unroll
        for (int ni = 0; ni < 2; ++ni)
            acc[mi][ni] = (f32x4){0.f, 0.f, 0.f, 0.f};

#pragma unroll
    for (int ks = 0; ks < 2; ++ks) {
        bf16x8 af[2], bf[2];
#pragma unroll
        for (int mi = 0; mi < 2; ++mi)
            af[mi] = *(const bf16x8*)(rb + (mi * 16 + l16) * 72 + ks * 32 + quad * 8);
#pragma unroll
        for (int ni = 0; ni < 2; ++ni)
            bf[ni] = *(const bf16x8*)(Wpt + (ni * 16 + l16) * 64 + ks * 32 + quad * 8);
#pragma unroll
        for (int mi = 0; mi < 2; ++mi)
#pragma unroll
            for (int ni = 0; ni < 2; ++ni)
                acc[mi][ni] = __builtin_amdgcn_mfma_f32_16x16x32_bf16(
                    af[mi], bf[ni], acc[mi][ni], 0, 0, 0);
    }

#pragma unroll
    for (int mi = 0; mi < 2; ++mi)
#pragma unroll
        for (int ni = 0; ni < 2; ++ni) {
            const int col = ni * 16 + l16;
            const float bv = bias[col];
#pragma unroll
            for (int rr = 0; rr < 4; ++rr) {
                const int row = mbase + mi * 16 + quad * 4 + rr;
                if (row < Mtot)
                    outt[(long)row * 32 + col] = f2b(fmaxf(acc[mi][ni][rr] + bv, 0.f));
            }
        }
}

// ---------------------------------------------------------------------------
// Generic NHWC conv, wave-synchronous, BK=64, register prefetch, both towers.
// Wave w owns rows [blk*128 + w*32, +32); private LDS double buffer
// [wave][2][32*72].  No __syncthreads anywhere.
// ---------------------------------------------------------------------------
template<int IC, int IH, int IW, int OC, int KH, int KW, int S, int OH, int OW>
__global__ __launch_bounds__(256) void convW_mfma(
    const u16* __restrict__ in, long inTs,
    const u16* __restrict__ Wp, int WpTs,
    const float* __restrict__ bias_v, const float* __restrict__ bias_a,
    u16* __restrict__ outp, long outTs, int Mtot)
{
    constexpr int OP  = OH * OW;
    constexpr int K   = KH * KW * IC;
    constexpr int NF  = OC / 16;
    constexpr int NCH = K / 64;

    __shared__ __attribute__((aligned(16))) u16 As[4 * 2 * 2304];

    const int tid = threadIdx.x;
    const int wave = tid >> 6, lane = tid & 63, quad = lane >> 4, l16 = lane & 15;
    const int t = blockIdx.y;
    const u16* int_ = in + (long)t * inTs;
    const u16* Wpt = Wp + (long)t * WpTs;
    const float* bias = t ? bias_a : bias_v;
    u16* outt = outp + (long)t * outTs;

    const int mbase = blockIdx.x * 128 + wave * 32;
    const int rl = lane >> 1, h = lane & 1;
    int m = mbase + rl; if (m > Mtot - 1) m = Mtot - 1;
    const int bl = m / OP, p = m % OP;
    const int oy = p / OW, ox = p % OW;
    const u16* abase = int_ + (((long)bl * IH + oy * S) * IW + ox * S) * IC + h * 32;

    u16* wbase = As + wave * 4608 + rl * 72 + h * 32;
    const u16* rbase = As + wave * 4608;

    f32x4 acc[2][NF];
#pragma unroll
    for (int mi = 0; mi < 2; ++mi)
#pragma unroll
        for (int ni = 0; ni < NF; ++ni)
            acc[mi][ni] = (f32x4){0.f, 0.f, 0.f, 0.f};

    // prefetch chunk 0 (offset 0)
    uint4 pre0, pre1, pre2, pre3;
    {
        const uint4* s = (const uint4*)abase;
        pre0 = s[0]; pre1 = s[1]; pre2 = s[2]; pre3 = s[3];
    }

#pragma unroll
    for (int c = 0; c < NCH; ++c) {
        {
            u16* dst = wbase + (c & 1) * 2304;
            *(uint4*)(dst)      = pre0;
            *(uint4*)(dst + 8)  = pre1;
            *(uint4*)(dst + 16) = pre2;
            *(uint4*)(dst + 24) = pre3;
        }
        if (c + 1 < NCH) {                       // next chunk's load in flight
            const int k0 = (c + 1) * 64;
            const int pos = k0 / IC;
            const int ky = pos / KW, kx = pos - ky * KW;
            const uint4* s = (const uint4*)(abase + ((long)ky * IW + kx) * IC);
            pre0 = s[0]; pre1 = s[1]; pre2 = s[2]; pre3 = s[3];
        }
        wave_lds_sync();                         // lgkm only; vm stays pending

        const u16* rb = rbase + (c & 1) * 2304;
#pragma unroll
        for (int ks = 0; ks < 2; ++ks) {
            const int k0 = c * 64;
            bf16x8 af[2], bf[NF];
#pragma unroll
            for (int mi = 0; mi < 2; ++mi)
                af[mi] = *(const bf16x8*)(rb + (mi * 16 + l16) * 72 + ks * 32 + quad * 8);
#pragma unroll
            for (int ni = 0; ni < NF; ++ni)
                bf[ni] = *(const bf16x8*)(Wpt + (long)(ni * 16 + l16) * K
                                           + k0 + ks * 32 + quad * 8);
#pragma unroll
            for (int mi = 0; mi < 2; ++mi)
#pragma unroll
                for (int ni = 0; ni < NF; ++ni)
                    acc[mi][ni] = __builtin_amdgcn_mfma_f32_16x16x32_bf16(
                        af[mi], bf[ni], acc[mi][ni], 0, 0, 0);
        }
        __builtin_amdgcn_wave_barrier();         // keep buffers from merging
    }

#pragma unroll
    for (int mi = 0; mi < 2; ++mi)
#pragma unroll
        for (int ni = 0; ni < NF; ++ni) {
            const int col = ni * 16 + l16;
            const float bv = bias[col];
#pragma unroll
            for (int rr = 0; rr < 4; ++rr) {
                const int row = mbase + mi * 16 + quad * 4 + rr;
                if (row < Mtot)
                    outt[(long)row * OC + col] = f2b(fmaxf(acc[mi][ni][rr] + bv, 0.f));
            }
        }
}

// ---------------------------------------------------------------------------
// Split-K MFMA GEMM with per-M-tile B select (unchanged).
// ---------------------------------------------------------------------------
#define LDSP 40
__global__ __launch_bounds__(256) void gemm_sk2(
    const u16* __restrict__ A, const u16* __restrict__ B0,
    const u16* __restrict__ B1,
    float* __restrict__ C, int M, int Mhalf, int N, int K, int Kc)
{
    __shared__ __attribute__((aligned(16))) u16 As[128 * LDSP];
    __shared__ __attribute__((aligned(16))) u16 Bs[128 * LDSP];

    const int tid  = threadIdx.x;
    const int wave = tid >> 6, lane = tid & 63;
    const int quad = lane >> 4, l16 = lane & 15;
    const int m0 = blockIdx.y * 128, n0 = blockIdx.x * 128;
    const u16* B = (m0 < Mhalf) ? B0 : B1;
    const int wm = (wave >> 1) * 64, wn = (wave & 1) * 64;
    const int kfrom = blockIdx.z * Kc;
    int kto = kfrom + Kc; if (kto > K) kto = K;

    f32x4 acc[4][4];
#pragma unroll
    for (int mi = 0; mi < 4; ++mi)
#pragma unroll
        for (int ni = 0; ni < 4; ++ni)
            acc[mi][ni] = (f32x4){0.f, 0.f, 0.f, 0.f};

    for (int k0 = kfrom; k0 < kto; k0 += 32) {
        __syncthreads();
#pragma unroll
        for (int pass = 0; pass < 2; ++pass) {
            int idx = tid + pass * 256;
            int r = idx >> 2, seg = idx & 3;
            int gr = m0 + r; if (gr > M - 1) gr = M - 1;
            uint4 va = *(const uint4*)(A + (long)gr * K + k0 + seg * 8);
            *(uint4*)(As + r * LDSP + seg * 8) = va;
            uint4 vb = *(const uint4*)(B + (long)(n0 + r) * K + k0 + seg * 8);
            *(uint4*)(Bs + r * LDSP + seg * 8) = vb;
        }
        __syncthreads();

        bf16x8 af[4], bfr[4];
#pragma unroll
        for (int mi = 0; mi < 4; ++mi)
            af[mi] = *(const bf16x8*)(As + (wm + mi * 16 + l16) * LDSP + quad * 8);
#pragma unroll
        for (int ni = 0; ni < 4; ++ni)
            bfr[ni] = *(const bf16x8*)(Bs + (wn + ni * 16 + l16) * LDSP + quad * 8);
#pragma unroll
        for (int mi = 0; mi < 4; ++mi)
#pragma unroll
            for (int ni = 0; ni < 4; ++ni)
                acc[mi][ni] = __builtin_amdgcn_mfma_f32_16x16x32_bf16(
                    af[mi], bfr[ni], acc[mi][ni], 0, 0, 0);
    }

#pragma unroll
    for (int mi = 0; mi < 4; ++mi)
#pragma unroll
        for (int ni = 0; ni < 4; ++ni) {
            int col = n0 + wn + ni * 16 + l16;
#pragma unroll
            for (int rr = 0; rr < 4; ++rr) {
                int row = m0 + wm + mi * 16 + quad * 4 + rr;
                if (row < M) atomicAdd(&C[(long)row * N + col], acc[mi][ni][rr]);
            }
        }
}

// ---------------------------------------------------------------------------
// Wl [512][3136] (k = oc*49+p) -> [n][p*64+oc] bf16 via LDS row transpose.
// ---------------------------------------------------------------------------
__global__ __launch_bounds__(256) void pack_wl(
    const float* __restrict__ vWl, const float* __restrict__ aWl,
    u16* __restrict__ dst)
{
    __shared__ float row[3136];
    const int bid = blockIdx.x, tid = threadIdx.x;
    const int n = bid & 511;
    const float* src = (bid < 512) ? vWl : aWl;
    for (int i = tid; i < 3136; i += 256)
        row[i] = src[(long)n * 3136 + i];
    __syncthreads();
    u16* d = dst + (long)bid * 3136;
    for (int i = tid; i < 3136; i += 256) {
        int p = i >> 6, oc = i & 63;
        d[i] = f2b(row[oc * 49 + p]);
    }
}

// ---------------------------------------------------------------------------
// All small weight packs + accumulator zeroing in ONE kernel (unchanged).
// ---------------------------------------------------------------------------
__global__ __launch_bounds__(256) void pack_misc(
    const float* __restrict__ vW1, const float* __restrict__ aW1,
    const float* __restrict__ vW2, const float* __restrict__ aW2,
    const float* __restrict__ vW3, const float* __restrict__ aW3,
    const float* __restrict__ avW, const float* __restrict__ aaW,
    const float* __restrict__ asW,
    const float* __restrict__ Wih, const float* __restrict__ Whh,
    u16* __restrict__ Wp1, u16* __restrict__ Wp2, u16* __restrict__ Wp3,
    u16* __restrict__ WTatt, u16* __restrict__ Bcat,
    float* __restrict__ zbase)
{
    const int idx = blockIdx.x * 256 + threadIdx.x;
    if (idx < 4096) {
        const float* s = (idx < 2048) ? vW1 : aW1;
        Wp1[idx] = f2b(s[idx & 2047]);
    } else if (idx < 69632) {
        int i = idx - 4096;
        const float* s = (i < 32768) ? vW2 : aW2;
        int j = i & 32767;
        int oc = j >> 9, kk = j & 511;
        int pos = kk >> 5, ic = kk & 31;
        int ky = pos >> 2, kx = pos & 3;
        Wp2[i] = f2b(s[((oc * 32 + ic) * 4 + ky) * 4 + kx]);
    } else if (idx < 143360) {
        int i = idx - 69632;
        const float* s = (i < 36864) ? vW3 : aW3;
        int j = i % 36864;
        int oc = j / 576, kk = j % 576;
        int pos = kk >> 6, ic = kk & 63;
        int ky = pos / 3, kx = pos % 3;
        Wp3[i] = f2b(s[((oc * 64 + ic) * 3 + ky) * 3 + kx]);
    } else if (idx < 180224) {
        int i = idx - 143360;
        int k = i >> 5, j = i & 31;
        float v = (k < 512) ? avW[(long)j * 512 + k]
                : (k < 1024) ? aaW[(long)j * 512 + (k - 512)]
                : asW[(long)j * 128 + (k - 1024)];
        WTatt[i] = f2b(v);
    } else if (idx < 507904) {
        int i = idx - 180224;
        int n = i / 640, k = i % 640;
        Bcat[i] = f2b((k < 512) ? Wih[(long)n * 512 + k]
                                : Whh[(long)n * 128 + (k - 512)]);
    } else {
        zbase[idx - 507904] = 0.f;
    }
}

// ---------------------------------------------------------------------------
// bias + ReLU + LayerNorm, both towers (unchanged).
// ---------------------------------------------------------------------------
__global__ __launch_bounds__(256) void ln_relu(
    const float* __restrict__ y,
    const float* __restrict__ bl_v, const float* __restrict__ bl_a,
    const float* __restrict__ g_v,  const float* __restrict__ g_a,
    const float* __restrict__ be_v, const float* __restrict__ be_a,
    float* __restrict__ outv)
{
    __shared__ float red[256];
    __shared__ float mean_s, inv_s;

    const int b = blockIdx.x, tid = threadIdx.x;
    const int t = b >> 10;
    const float* bias = t ? bl_a : bl_v;
    const float* g    = t ? g_a  : g_v;
    const float* be   = t ? be_a : be_v;
    const float* yr = y + (long)b * 512;

    float v0 = fmaxf(yr[tid]       + bias[tid],       0.f);
    float v1 = fmaxf(yr[tid + 256] + bias[tid + 256], 0.f);

    red[tid] = v0 + v1;
    __syncthreads();
    for (int s = 128; s > 0; s >>= 1) { if (tid < s) red[tid] += red[tid + s]; __syncthreads(); }
    if (tid == 0) mean_s = red[0] * (1.f / 512.f);
    __syncthreads();
    float mean = mean_s;
    float d0 = v0 - mean, d1 = v1 - mean;
    red[tid] = d0 * d0 + d1 * d1;
    __syncthreads();
    for (int s = 128; s > 0; s >>= 1) { if (tid < s) red[tid] += red[tid + s]; __syncthreads(); }
    if (tid == 0) inv_s = rsqrtf(red[0] * (1.f / 512.f) + 1e-5f);
    __syncthreads();
    float inv = inv_s;

    outv[(long)b * 512 + tid]       = d0 * inv * g[tid]       + be[tid];
    outv[(long)b * 512 + tid + 256] = d1 * inv * g[tid + 256] + be[tid + 256];
}

// ---------------------------------------------------------------------------
// Attention gating (unchanged).
// ---------------------------------------------------------------------------
__global__ __launch_bounds__(256) void attn_fuse(
    const float* __restrict__ vff, const float* __restrict__ aff,
    const float* __restrict__ h0, const float* __restrict__ done,
    const u16* __restrict__ WT,
    const float* __restrict__ avb, const float* __restrict__ aab,
    const float* __restrict__ asb,
    const float* __restrict__ attW, const float* __restrict__ attb,
    u16* __restrict__ Acat)
{
    __shared__ float vs[512], afs[512], hs[128], part[8][32], act[32], wsm[2];
    const int b = blockIdx.x, tid = threadIdx.x;

    for (int i = tid; i < 512; i += 256) {
        vs[i]  = vff[(long)b * 512 + i];
        afs[i] = aff[(long)b * 512 + i];
    }
    if (tid < 128) hs[tid] = h0[b * 128 + tid];
    __syncthreads();

    {
        const int j = tid & 31, g = tid >> 5;
        float a = 0.f;
#pragma unroll 8
        for (int k = g * 64; k < g * 64 + 64; ++k)
            a += vs[k] * b2f(WT[k * 32 + j]);
#pragma unroll 8
        for (int k = g * 64; k < g * 64 + 64; ++k)
            a += afs[k] * b2f(WT[(512 + k) * 32 + j]);
#pragma unroll 8
        for (int k = g * 16; k < g * 16 + 16; ++k)
            a += hs[k] * b2f(WT[(1024 + k) * 32 + j]);
        part[g][j] = a;
    }
    __syncthreads();
    if (tid < 32) {
        float a = avb[tid] + aab[tid] + asb[tid];
#pragma unroll
        for (int g2 = 0; g2 < 8; ++g2) a += part[g2][tid];
        act[tid] = tanhf(a);
    }
    __syncthreads();
    if (tid == 0) {
        float l0 = attb[0], l1 = attb[1];
        for (int j = 0; j < 32; ++j) {
            l0 += act[j] * attW[j];
            l1 += act[j] * attW[32 + j];
        }
        float mx = fmaxf(l0, l1);
        float e0 = expf(l0 - mx), e1 = expf(l1 - mx);
        float s = e0 + e1;
        wsm[0] = e0 / s; wsm[1] = e1 / s;
    }
    __syncthreads();
    const float w0 = wsm[0], w1 = wsm[1];
    const float m = 1.f - done[b];
    for (int i = tid; i < 512; i += 256)
        Acat[(long)b * 640 + i] = f2b(w0 * vs[i] + w1 * afs[i]);
    if (tid < 128)
        Acat[(long)b * 640 + 512 + tid] = f2b(m * hs[tid]);
}

// ---------------------------------------------------------------------------
// LSTM pointwise epilogue (unchanged).
// ---------------------------------------------------------------------------
__global__ __launch_bounds__(128) void lstm_fin(
    const float* __restrict__ gates,
    const float* __restrict__ bih, const float* __restrict__ bhh,
    const float* __restrict__ c0, const float* __restrict__ done,
    float* __restrict__ out)
{
    const int b = blockIdx.x, j = threadIdx.x;
    const float* G = gates + (long)b * 512;
    float gi = G[j]       + bih[j]       + bhh[j];
    float gf = G[128 + j] + bih[128 + j] + bhh[128 + j];
    float gg = G[256 + j] + bih[256 + j] + bhh[256 + j];
    float go = G[384 + j] + bih[384 + j] + bhh[384 + j];
    float m  = 1.f - done[b];
    float c  = m * c0[b * 128 + j];
    float si = 1.f / (1.f + expf(-gi));
    float sf = 1.f / (1.f + expf(-gf));
    float so = 1.f / (1.f + expf(-go));
    float cn = sf * c + si * tanhf(gg);
    float hn = so * tanhf(cn);
    out[b * 128 + j]          = hn;
    out[131072 + b * 128 + j] = cn;
}

// ---------------------------------------------------------------------------
extern "C" void kernel_launch(void* const* d_in, const int* in_sizes, int n_in,
                              void* d_out, int out_size, void* d_ws, size_t ws_size,
                              hipStream_t stream)
{
    (void)in_sizes; (void)n_in; (void)out_size;

    const float* x     = (const float*)d_in[0];
    const float* done  = (const float*)d_in[1];
    const float* h0    = (const float*)d_in[2];
    const float* c0in  = (const float*)d_in[3];
    const float* vW1   = (const float*)d_in[4];
    const float* vb1   = (const float*)d_in[5];
    const float* vW2   = (const float*)d_in[6];
    const float* vb2   = (const float*)d_in[7];
    const float* vW3   = (const float*)d_in[8];
    const float* vb3   = (const float*)d_in[9];
    const float* vWl   = (const float*)d_in[10];
    const float* vbl   = (const float*)d_in[11];
    const float* aW1   = (const float*)d_in[12];
    const float* ab1   = (const float*)d_in[13];
    const float* aW2   = (const float*)d_in[14];
    const float* ab2   = (const float*)d_in[15];
    const float* aW3   = (const float*)d_in[16];
    const float* ab3   = (const float*)d_in[17];
    const float* aWl   = (const float*)d_in[18];
    const float* abl   = (const float*)d_in[19];
    const float* vln_g = (const float*)d_in[20];
    const float* vln_b = (const float*)d_in[21];
    const float* aln_g = (const float*)d_in[22];
    const float* aln_b = (const float*)d_in[23];
    const float* att_vW = (const float*)d_in[24];
    const float* att_vb = (const float*)d_in[25];
    const float* att_aW = (const float*)d_in[26];
    const float* att_ab = (const float*)d_in[27];
    const float* att_sW = (const float*)d_in[28];
    const float* att_sb = (const float*)d_in[29];
    const float* attW  = (const float*)d_in[30];
    const float* attb  = (const float*)d_in[31];
    const float* Wih   = (const float*)d_in[32];
    const float* Whh   = (const float*)d_in[33];
    const float* bih   = (const float*)d_in[34];
    const float* bhh   = (const float*)d_in[35];

    float* out = (float*)d_out;
    float* vfaf = out + 262144;   // [2048][512] f32 (vf then af)

    // ---- adaptive batch chunk ----
    const size_t PERBATCH = 2ul * (12800 + 5184) * 2;   // c1 + c2, both towers
    const size_t PERSIST  =
          1024ul * 512 * 4       // gates
        + 2048ul * 512 * 4       // ych (both towers)
        + 1024ul * 640 * 2       // Acat
        + 512ul * 640 * 2        // Bcat
        + 2ul * 512 * 3136 * 2   // Wlb
        + 2ul * 2048 * 2         // Wp1
        + 2ul * 32768 * 2        // Wp2
        + 2ul * 36864 * 2        // Wp3
        + 36864ul * 2            // WTatt
        + 2ul * 1024 * 3136 * 2; // c3f (both towers)
    int NB = 64;
    const int cands[4] = {1024, 512, 256, 128};
    for (int i = 0; i < 4; ++i)
        if (PERSIST + (size_t)cands[i] * PERBATCH <= ws_size) { NB = cands[i]; break; }
    const int NC = 1024 / NB;

    // ---- workspace carve (gates then ych contiguous for pack_misc zeroing) --
    char* p = (char*)d_ws;
    float* gates = (float*)p; p += 1024ul * 512 * 4;
    float* ych   = (float*)p; p += 2048ul * 512 * 4;
    u16*   Acat  = (u16*)p;   p += 1024ul * 640 * 2;
    u16*   Bcat  = (u16*)p;   p += 512ul * 640 * 2;
    u16*   Wlb   = (u16*)p;   p += 2ul * 512 * 3136 * 2;
    u16*   Wp1   = (u16*)p;   p += 2ul * 2048 * 2;
    u16*   Wp2   = (u16*)p;   p += 2ul * 32768 * 2;
    u16*   Wp3   = (u16*)p;   p += 2ul * 36864 * 2;
    u16*   WTatt = (u16*)p;   p += 36864ul * 2;
    u16*   c3f   = (u16*)p;   p += 2ul * 1024 * 3136 * 2;
    u16*   c1    = (u16*)p;   p += 2ul * NB * 12800 * 2;
    u16*   c2    = (u16*)p;

    // 1) packs + zeros
    hipLaunchKernelGGL(pack_wl, dim3(1024), dim3(256), 0, stream, vWl, aWl, Wlb);
    hipLaunchKernelGGL(pack_misc, dim3(8128), dim3(256), 0, stream,
        vW1, aW1, vW2, aW2, vW3, aW3, att_vW, att_aW, att_sW, Wih, Whh,
        Wp1, Wp2, Wp3, WTatt, Bcat, gates);

    // 2) conv towers (wave-synchronous; both towers via blockIdx.y)
    for (int cch = 0; cch < NC; ++cch) {
        const int b0 = cch * NB;
        const int M1 = NB * 400, M2 = NB * 81, M3 = NB * 49;

        hipLaunchKernelGGL(conv1_mfma, dim3(M1 / 128, 2), dim3(256), 0, stream,
            x, (long)b0 * 14112, Wp1, vb1, ab1, c1, M1);

        hipLaunchKernelGGL((convW_mfma<32, 20, 20, 64, 4, 4, 2, 9, 9>),
            dim3((M2 + 127) / 128, 2), dim3(256), 0, stream,
            c1, (long)NB * 12800, Wp2, 32768, vb2, ab2,
            c2, (long)NB * 5184, M2);

        hipLaunchKernelGGL((convW_mfma<64, 9, 9, 64, 3, 3, 1, 7, 7>),
            dim3((M3 + 127) / 128, 2), dim3(256), 0, stream,
            c2, (long)NB * 5184, Wp3, 36864, vb3, ab3,
            c3f + (long)b0 * 3136, 1024l * 3136, M3);
    }

    // 3) tower linears as one M=2048 GEMM (B switches at row 1024), split-K 7
    hipLaunchKernelGGL(gemm_sk2, dim3(4, 16, 7), dim3(256), 0, stream,
        c3f, Wlb, Wlb + 512ul * 3136, ych, 2048, 1024, 512, 3136, 448);

    // 4) LN both towers -> vf/af f32 slots in d_out
    hipLaunchKernelGGL(ln_relu, dim3(2048), dim3(256), 0, stream,
        ych, vbl, abl, vln_g, aln_g, vln_b, aln_b, vfaf);

    // 5) attention gating -> Acat
    hipLaunchKernelGGL(attn_fuse, dim3(1024), dim3(256), 0, stream,
        vfaf, vfaf + 1024ul * 512, h0, done, WTatt,
        att_vb, att_ab, att_sb, attW, attb, Acat);

    // 6) gates GEMM (split-K 4)
    hipLaunchKernelGGL(gemm_sk2, dim3(4, 8, 4), dim3(256), 0, stream,
        Acat, Bcat, Bcat, gates, 1024, 1 << 30, 512, 640, 160);

    // 7) LSTM epilogue
    hipLaunchKernelGGL(lstm_fin, dim3(1024), dim3(128), 0, stream,
        gates, bih, bhh, c0in, done, out);
}

// Round 13
// 318.734 us; speedup vs baseline: 1.1840x; 1.1840x over previous
//
#include <hip/hip_runtime.h>

// ---------------------------------------------------------------------------
// AlignableCaslAgent forward.  Inputs f32, outputs f32 (verified rounds 4-12).
// Round 12: conv weights repacked into MFMA-FRAGMENT ORDER (Wf[frag][lane][8],
// lane-contiguous 16B) - kills the 64-transaction-per-instruction weight-load
// serialization that pinned conv2 at 66us across occupancy 24-67%, with/out
// barriers, with/out prefetch (rounds 8-12 invariance).
// ---------------------------------------------------------------------------

typedef unsigned short u16;
typedef unsigned int u32;
typedef __attribute__((ext_vector_type(8))) short bf16x8;
typedef __attribute__((ext_vector_type(4))) float f32x4;

__device__ __forceinline__ float b2f(u16 u) {
    union { u32 i; float f; } v; v.i = ((u32)u) << 16; return v.f;
}
__device__ __forceinline__ u16 f2b(float f) {
    union { float f; u32 i; } v; v.f = f;
    u32 r = v.i + 0x7fffu + ((v.i >> 16) & 1u);
    return (u16)(r >> 16);
}
// wave-local LDS sync: fence + drain lgkmcnt only (vm loads stay in flight)
__device__ __forceinline__ void wave_lds_sync() {
    __builtin_amdgcn_wave_barrier();
    __builtin_amdgcn_s_waitcnt(0xC07F);
    __builtin_amdgcn_wave_barrier();
}

// ---------------------------------------------------------------------------
// conv1, wave-synchronous, fragment-order weights.
// Wp1f layout: [t][frag=ks*2+ni][lane][8] bf16 (frag of 16x16x32 B-operand).
// ---------------------------------------------------------------------------
__global__ __launch_bounds__(256) void conv1_mfma(
    const float* __restrict__ x, long boff,
    const u16* __restrict__ Wp,
    const float* __restrict__ bias_v, const float* __restrict__ bias_a,
    u16* __restrict__ outp, int Mtot)
{
    __shared__ __attribute__((aligned(16))) u16 As[4 * 2304];   // [wave][32*72]

    const int tid = threadIdx.x;
    const int wave = tid >> 6, lane = tid & 63, quad = lane >> 4, l16 = lane & 15;
    const int t = blockIdx.y;
    const u16* Wpt = Wp + t * 2048;
    const float* bias = t ? bias_a : bias_v;
    u16* outt = outp + (long)t * Mtot * 32;

    const int mbase = blockIdx.x * 128 + wave * 32;
    const int rl = lane >> 1, h = lane & 1;
    int m = mbase + rl; if (m > Mtot - 1) m = Mtot - 1;
    const int bl = m / 400, p = m % 400;
    const int oy = p / 20, ox = p % 20;
    const float* F = x + boff + (long)bl * 14112 + t * 7056
                     + (long)(oy * 4) * 84 + ox * 4;

    {
        u16 tmp[32];
#pragma unroll
        for (int rr = 0; rr < 4; ++rr) {
            const int ky = h * 4 + rr;
            float4 v0 = *(const float4*)(F + ky * 84);
            float4 v1 = *(const float4*)(F + ky * 84 + 4);
            tmp[rr * 8 + 0] = f2b(v0.x); tmp[rr * 8 + 1] = f2b(v0.y);
            tmp[rr * 8 + 2] = f2b(v0.z); tmp[rr * 8 + 3] = f2b(v0.w);
            tmp[rr * 8 + 4] = f2b(v1.x); tmp[rr * 8 + 5] = f2b(v1.y);
            tmp[rr * 8 + 6] = f2b(v1.z); tmp[rr * 8 + 7] = f2b(v1.w);
        }
        u16* dst = As + wave * 2304 + rl * 72 + h * 32;
        const uint4* s = (const uint4*)tmp;
        *(uint4*)(dst)      = s[0];
        *(uint4*)(dst + 8)  = s[1];
        *(uint4*)(dst + 16) = s[2];
        *(uint4*)(dst + 24) = s[3];
    }
    wave_lds_sync();

    const u16* rb = As + wave * 2304;
    f32x4 acc[2][2];
#pragma unroll
    for (int mi = 0; mi < 2; ++mi)
#pragma unroll
        for (int ni = 0; ni < 2; ++ni)
            acc[mi][ni] = (f32x4){0.f, 0.f, 0.f, 0.f};

#pragma unroll
    for (int ks = 0; ks < 2; ++ks) {
        bf16x8 af[2], bf[2];
#pragma unroll
        for (int mi = 0; mi < 2; ++mi)
            af[mi] = *(const bf16x8*)(rb + (mi * 16 + l16) * 72 + ks * 32 + quad * 8);
#pragma unroll
        for (int ni = 0; ni < 2; ++ni)
            bf[ni] = *(const bf16x8*)(Wpt + ((ks * 2 + ni) * 64 + lane) * 8);
#pragma unroll
        for (int mi = 0; mi < 2; ++mi)
#pragma unroll
            for (int ni = 0; ni < 2; ++ni)
                acc[mi][ni] = __builtin_amdgcn_mfma_f32_16x16x32_bf16(
                    af[mi], bf[ni], acc[mi][ni], 0, 0, 0);
    }

#pragma unroll
    for (int mi = 0; mi < 2; ++mi)
#pragma unroll
        for (int ni = 0; ni < 2; ++ni) {
            const int col = ni * 16 + l16;
            const float bv = bias[col];
#pragma unroll
            for (int rr = 0; rr < 4; ++rr) {
                const int row = mbase + mi * 16 + quad * 4 + rr;
                if (row < Mtot)
                    outt[(long)row * 32 + col] = f2b(fmaxf(acc[mi][ni][rr] + bv, 0.f));
            }
        }
}

// ---------------------------------------------------------------------------
// Generic NHWC conv, wave-synchronous, BK=64, register prefetch, both towers.
// Weights in fragment order: Wf[((c*2+ks)*NF+ni)][lane][8] - one contiguous
// 1KB wave-read per fragment (was 64 separate 1KB-strided transactions).
// ---------------------------------------------------------------------------
template<int IC, int IH, int IW, int OC, int KH, int KW, int S, int OH, int OW>
__global__ __launch_bounds__(256) void convW_mfma(
    const u16* __restrict__ in, long inTs,
    const u16* __restrict__ Wp, int WpTs,
    const float* __restrict__ bias_v, const float* __restrict__ bias_a,
    u16* __restrict__ outp, long outTs, int Mtot)
{
    constexpr int OP  = OH * OW;
    constexpr int K   = KH * KW * IC;
    constexpr int NF  = OC / 16;
    constexpr int NCH = K / 64;

    __shared__ __attribute__((aligned(16))) u16 As[4 * 2 * 2304];

    const int tid = threadIdx.x;
    const int wave = tid >> 6, lane = tid & 63, quad = lane >> 4, l16 = lane & 15;
    const int t = blockIdx.y;
    const u16* int_ = in + (long)t * inTs;
    const u16* Wpt = Wp + (long)t * WpTs;
    const float* bias = t ? bias_a : bias_v;
    u16* outt = outp + (long)t * outTs;

    const int mbase = blockIdx.x * 128 + wave * 32;
    const int rl = lane >> 1, h = lane & 1;
    int m = mbase + rl; if (m > Mtot - 1) m = Mtot - 1;
    const int bl = m / OP, p = m % OP;
    const int oy = p / OW, ox = p % OW;
    const u16* abase = int_ + (((long)bl * IH + oy * S) * IW + ox * S) * IC + h * 32;

    u16* wbase = As + wave * 4608 + rl * 72 + h * 32;
    const u16* rbase = As + wave * 4608;

    f32x4 acc[2][NF];
#pragma unroll
    for (int mi = 0; mi < 2; ++mi)
#pragma unroll
        for (int ni = 0; ni < NF; ++ni)
            acc[mi][ni] = (f32x4){0.f, 0.f, 0.f, 0.f};

    uint4 pre0, pre1, pre2, pre3;
    {
        const uint4* s = (const uint4*)abase;
        pre0 = s[0]; pre1 = s[1]; pre2 = s[2]; pre3 = s[3];
    }

#pragma unroll
    for (int c = 0; c < NCH; ++c) {
        {
            u16* dst = wbase + (c & 1) * 2304;
            *(uint4*)(dst)      = pre0;
            *(uint4*)(dst + 8)  = pre1;
            *(uint4*)(dst + 16) = pre2;
            *(uint4*)(dst + 24) = pre3;
        }
        if (c + 1 < NCH) {
            const int k0 = (c + 1) * 64;
            const int pos = k0 / IC;
            const int ky = pos / KW, kx = pos - ky * KW;
            const uint4* s = (const uint4*)(abase + ((long)ky * IW + kx) * IC);
            pre0 = s[0]; pre1 = s[1]; pre2 = s[2]; pre3 = s[3];
        }
        wave_lds_sync();

        const u16* rb = rbase + (c & 1) * 2304;
#pragma unroll
        for (int ks = 0; ks < 2; ++ks) {
            bf16x8 af[2], bf[NF];
#pragma unroll
            for (int mi = 0; mi < 2; ++mi)
                af[mi] = *(const bf16x8*)(rb + (mi * 16 + l16) * 72 + ks * 32 + quad * 8);
#pragma unroll
            for (int ni = 0; ni < NF; ++ni)
                bf[ni] = *(const bf16x8*)(Wpt + (((c * 2 + ks) * NF + ni) * 64 + lane) * 8);
#pragma unroll
            for (int mi = 0; mi < 2; ++mi)
#pragma unroll
                for (int ni = 0; ni < NF; ++ni)
                    acc[mi][ni] = __builtin_amdgcn_mfma_f32_16x16x32_bf16(
                        af[mi], bf[ni], acc[mi][ni], 0, 0, 0);
        }
        __builtin_amdgcn_wave_barrier();
    }

#pragma unroll
    for (int mi = 0; mi < 2; ++mi)
#pragma unroll
        for (int ni = 0; ni < NF; ++ni) {
            const int col = ni * 16 + l16;
            const float bv = bias[col];
#pragma unroll
            for (int rr = 0; rr < 4; ++rr) {
                const int row = mbase + mi * 16 + quad * 4 + rr;
                if (row < Mtot)
                    outt[(long)row * OC + col] = f2b(fmaxf(acc[mi][ni][rr] + bv, 0.f));
            }
        }
}

// ---------------------------------------------------------------------------
// Split-K MFMA GEMM with per-M-tile B select (unchanged).
// ---------------------------------------------------------------------------
#define LDSP 40
__global__ __launch_bounds__(256) void gemm_sk2(
    const u16* __restrict__ A, const u16* __restrict__ B0,
    const u16* __restrict__ B1,
    float* __restrict__ C, int M, int Mhalf, int N, int K, int Kc)
{
    __shared__ __attribute__((aligned(16))) u16 As[128 * LDSP];
    __shared__ __attribute__((aligned(16))) u16 Bs[128 * LDSP];

    const int tid  = threadIdx.x;
    const int wave = tid >> 6, lane = tid & 63;
    const int quad = lane >> 4, l16 = lane & 15;
    const int m0 = blockIdx.y * 128, n0 = blockIdx.x * 128;
    const u16* B = (m0 < Mhalf) ? B0 : B1;
    const int wm = (wave >> 1) * 64, wn = (wave & 1) * 64;
    const int kfrom = blockIdx.z * Kc;
    int kto = kfrom + Kc; if (kto > K) kto = K;

    f32x4 acc[4][4];
#pragma unroll
    for (int mi = 0; mi < 4; ++mi)
#pragma unroll
        for (int ni = 0; ni < 4; ++ni)
            acc[mi][ni] = (f32x4){0.f, 0.f, 0.f, 0.f};

    for (int k0 = kfrom; k0 < kto; k0 += 32) {
        __syncthreads();
#pragma unroll
        for (int pass = 0; pass < 2; ++pass) {
            int idx = tid + pass * 256;
            int r = idx >> 2, seg = idx & 3;
            int gr = m0 + r; if (gr > M - 1) gr = M - 1;
            uint4 va = *(const uint4*)(A + (long)gr * K + k0 + seg * 8);
            *(uint4*)(As + r * LDSP + seg * 8) = va;
            uint4 vb = *(const uint4*)(B + (long)(n0 + r) * K + k0 + seg * 8);
            *(uint4*)(Bs + r * LDSP + seg * 8) = vb;
        }
        __syncthreads();

        bf16x8 af[4], bfr[4];
#pragma unroll
        for (int mi = 0; mi < 4; ++mi)
            af[mi] = *(const bf16x8*)(As + (wm + mi * 16 + l16) * LDSP + quad * 8);
#pragma unroll
        for (int ni = 0; ni < 4; ++ni)
            bfr[ni] = *(const bf16x8*)(Bs + (wn + ni * 16 + l16) * LDSP + quad * 8);
#pragma unroll
        for (int mi = 0; mi < 4; ++mi)
#pragma unroll
            for (int ni = 0; ni < 4; ++ni)
                acc[mi][ni] = __builtin_amdgcn_mfma_f32_16x16x32_bf16(
                    af[mi], bfr[ni], acc[mi][ni], 0, 0, 0);
    }

#pragma unroll
    for (int mi = 0; mi < 4; ++mi)
#pragma unroll
        for (int ni = 0; ni < 4; ++ni) {
            int col = n0 + wn + ni * 16 + l16;
#pragma unroll
            for (int rr = 0; rr < 4; ++rr) {
                int row = m0 + wm + mi * 16 + quad * 4 + rr;
                if (row < M) atomicAdd(&C[(long)row * N + col], acc[mi][ni][rr]);
            }
        }
}

// ---------------------------------------------------------------------------
// Wl [512][3136] (k = oc*49+p) -> [n][p*64+oc] bf16 via LDS row transpose.
// ---------------------------------------------------------------------------
__global__ __launch_bounds__(256) void pack_wl(
    const float* __restrict__ vWl, const float* __restrict__ aWl,
    u16* __restrict__ dst)
{
    __shared__ float row[3136];
    const int bid = blockIdx.x, tid = threadIdx.x;
    const int n = bid & 511;
    const float* src = (bid < 512) ? vWl : aWl;
    for (int i = tid; i < 3136; i += 256)
        row[i] = src[(long)n * 3136 + i];
    __syncthreads();
    u16* d = dst + (long)bid * 3136;
    for (int i = tid; i < 3136; i += 256) {
        int p = i >> 6, oc = i & 63;
        d[i] = f2b(row[oc * 49 + p]);
    }
}

// ---------------------------------------------------------------------------
// All small weight packs + accumulator zeroing in ONE kernel.
// Conv weights now packed in MFMA-fragment order (see conv kernels).
// ---------------------------------------------------------------------------
__global__ __launch_bounds__(256) void pack_misc(
    const float* __restrict__ vW1, const float* __restrict__ aW1,
    const float* __restrict__ vW2, const float* __restrict__ aW2,
    const float* __restrict__ vW3, const float* __restrict__ aW3,
    const float* __restrict__ avW, const float* __restrict__ aaW,
    const float* __restrict__ asW,
    const float* __restrict__ Wih, const float* __restrict__ Whh,
    u16* __restrict__ Wp1, u16* __restrict__ Wp2, u16* __restrict__ Wp3,
    u16* __restrict__ WTatt, u16* __restrict__ Bcat,
    float* __restrict__ zbase)
{
    const int idx = blockIdx.x * 256 + threadIdx.x;
    if (idx < 4096) {                // Wp1f: [t][ks*2+ni][lane][8], K=64, NF=2
        const float* s = (idx < 2048) ? vW1 : aW1;
        int j0 = idx & 2047;
        int jj = j0 & 7, lane = (j0 >> 3) & 63, rest = j0 >> 9;
        int ni = rest & 1, ks = rest >> 1;
        int oc = ni * 16 + (lane & 15);
        int k  = ks * 32 + (lane >> 4) * 8 + jj;
        Wp1[idx] = f2b(s[oc * 64 + k]);
    } else if (idx < 69632) {        // Wp2f: K=512, IC=32, KW=4, NF=4
        int i = idx - 4096;
        const float* s = (i < 32768) ? vW2 : aW2;
        int j0 = i & 32767;
        int jj = j0 & 7, lane = (j0 >> 3) & 63, rest = j0 >> 9;
        int ni = rest & 3, rest2 = rest >> 2;
        int ks = rest2 & 1, c = rest2 >> 1;
        int oc = ni * 16 + (lane & 15);
        int k  = c * 64 + ks * 32 + (lane >> 4) * 8 + jj;
        int pos = k >> 5, ic = k & 31;
        int ky = pos >> 2, kx = pos & 3;
        Wp2[i] = f2b(s[((oc * 32 + ic) * 4 + ky) * 4 + kx]);
    } else if (idx < 143360) {       // Wp3f: K=576, IC=64, KW=3, NF=4
        int i = idx - 69632;
        const float* s = (i < 36864) ? vW3 : aW3;
        int j0 = i % 36864;
        int jj = j0 & 7, lane = (j0 >> 3) & 63, rest = j0 >> 9;
        int ni = rest & 3, rest2 = rest >> 2;
        int ks = rest2 & 1, c = rest2 >> 1;
        int oc = ni * 16 + (lane & 15);
        int k  = c * 64 + ks * 32 + (lane >> 4) * 8 + jj;
        int pos = k >> 6, ic = k & 63;
        int ky = pos / 3, kx = pos % 3;
        Wp3[i] = f2b(s[((oc * 64 + ic) * 3 + ky) * 3 + kx]);
    } else if (idx < 180224) {       // WTatt: [1152][32]
        int i = idx - 143360;
        int k = i >> 5, j = i & 31;
        float v = (k < 512) ? avW[(long)j * 512 + k]
                : (k < 1024) ? aaW[(long)j * 512 + (k - 512)]
                : asW[(long)j * 128 + (k - 1024)];
        WTatt[i] = f2b(v);
    } else if (idx < 507904) {       // Bcat: [512][640]
        int i = idx - 180224;
        int n = i / 640, k = i % 640;
        Bcat[i] = f2b((k < 512) ? Wih[(long)n * 512 + k]
                                : Whh[(long)n * 128 + (k - 512)]);
    } else {                         // zero gates+ych
        zbase[idx - 507904] = 0.f;
    }
}

// ---------------------------------------------------------------------------
// bias + ReLU + LayerNorm, both towers (unchanged).
// ---------------------------------------------------------------------------
__global__ __launch_bounds__(256) void ln_relu(
    const float* __restrict__ y,
    const float* __restrict__ bl_v, const float* __restrict__ bl_a,
    const float* __restrict__ g_v,  const float* __restrict__ g_a,
    const float* __restrict__ be_v, const float* __restrict__ be_a,
    float* __restrict__ outv)
{
    __shared__ float red[256];
    __shared__ float mean_s, inv_s;

    const int b = blockIdx.x, tid = threadIdx.x;
    const int t = b >> 10;
    const float* bias = t ? bl_a : bl_v;
    const float* g    = t ? g_a  : g_v;
    const float* be   = t ? be_a : be_v;
    const float* yr = y + (long)b * 512;

    float v0 = fmaxf(yr[tid]       + bias[tid],       0.f);
    float v1 = fmaxf(yr[tid + 256] + bias[tid + 256], 0.f);

    red[tid] = v0 + v1;
    __syncthreads();
    for (int s = 128; s > 0; s >>= 1) { if (tid < s) red[tid] += red[tid + s]; __syncthreads(); }
    if (tid == 0) mean_s = red[0] * (1.f / 512.f);
    __syncthreads();
    float mean = mean_s;
    float d0 = v0 - mean, d1 = v1 - mean;
    red[tid] = d0 * d0 + d1 * d1;
    __syncthreads();
    for (int s = 128; s > 0; s >>= 1) { if (tid < s) red[tid] += red[tid + s]; __syncthreads(); }
    if (tid == 0) inv_s = rsqrtf(red[0] * (1.f / 512.f) + 1e-5f);
    __syncthreads();
    float inv = inv_s;

    outv[(long)b * 512 + tid]       = d0 * inv * g[tid]       + be[tid];
    outv[(long)b * 512 + tid + 256] = d1 * inv * g[tid + 256] + be[tid + 256];
}

// ---------------------------------------------------------------------------
// Attention gating (unchanged).
// ---------------------------------------------------------------------------
__global__ __launch_bounds__(256) void attn_fuse(
    const float* __restrict__ vff, const float* __restrict__ aff,
    const float* __restrict__ h0, const float* __restrict__ done,
    const u16* __restrict__ WT,
    const float* __restrict__ avb, const float* __restrict__ aab,
    const float* __restrict__ asb,
    const float* __restrict__ attW, const float* __restrict__ attb,
    u16* __restrict__ Acat)
{
    __shared__ float vs[512], afs[512], hs[128], part[8][32], act[32], wsm[2];
    const int b = blockIdx.x, tid = threadIdx.x;

    for (int i = tid; i < 512; i += 256) {
        vs[i]  = vff[(long)b * 512 + i];
        afs[i] = aff[(long)b * 512 + i];
    }
    if (tid < 128) hs[tid] = h0[b * 128 + tid];
    __syncthreads();

    {
        const int j = tid & 31, g = tid >> 5;
        float a = 0.f;
#pragma unroll 8
        for (int k = g * 64; k < g * 64 + 64; ++k)
            a += vs[k] * b2f(WT[k * 32 + j]);
#pragma unroll 8
        for (int k = g * 64; k < g * 64 + 64; ++k)
            a += afs[k] * b2f(WT[(512 + k) * 32 + j]);
#pragma unroll 8
        for (int k = g * 16; k < g * 16 + 16; ++k)
            a += hs[k] * b2f(WT[(1024 + k) * 32 + j]);
        part[g][j] = a;
    }
    __syncthreads();
    if (tid < 32) {
        float a = avb[tid] + aab[tid] + asb[tid];
#pragma unroll
        for (int g2 = 0; g2 < 8; ++g2) a += part[g2][tid];
        act[tid] = tanhf(a);
    }
    __syncthreads();
    if (tid == 0) {
        float l0 = attb[0], l1 = attb[1];
        for (int j = 0; j < 32; ++j) {
            l0 += act[j] * attW[j];
            l1 += act[j] * attW[32 + j];
        }
        float mx = fmaxf(l0, l1);
        float e0 = expf(l0 - mx), e1 = expf(l1 - mx);
        float s = e0 + e1;
        wsm[0] = e0 / s; wsm[1] = e1 / s;
    }
    __syncthreads();
    const float w0 = wsm[0], w1 = wsm[1];
    const float m = 1.f - done[b];
    for (int i = tid; i < 512; i += 256)
        Acat[(long)b * 640 + i] = f2b(w0 * vs[i] + w1 * afs[i]);
    if (tid < 128)
        Acat[(long)b * 640 + 512 + tid] = f2b(m * hs[tid]);
}

// ---------------------------------------------------------------------------
// LSTM pointwise epilogue (unchanged).
// ---------------------------------------------------------------------------
__global__ __launch_bounds__(128) void lstm_fin(
    const float* __restrict__ gates,
    const float* __restrict__ bih, const float* __restrict__ bhh,
    const float* __restrict__ c0, const float* __restrict__ done,
    float* __restrict__ out)
{
    const int b = blockIdx.x, j = threadIdx.x;
    const float* G = gates + (long)b * 512;
    float gi = G[j]       + bih[j]       + bhh[j];
    float gf = G[128 + j] + bih[128 + j] + bhh[128 + j];
    float gg = G[256 + j] + bih[256 + j] + bhh[256 + j];
    float go = G[384 + j] + bih[384 + j] + bhh[384 + j];
    float m  = 1.f - done[b];
    float c  = m * c0[b * 128 + j];
    float si = 1.f / (1.f + expf(-gi));
    float sf = 1.f / (1.f + expf(-gf));
    float so = 1.f / (1.f + expf(-go));
    float cn = sf * c + si * tanhf(gg);
    float hn = so * tanhf(cn);
    out[b * 128 + j]          = hn;
    out[131072 + b * 128 + j] = cn;
}

// ---------------------------------------------------------------------------
extern "C" void kernel_launch(void* const* d_in, const int* in_sizes, int n_in,
                              void* d_out, int out_size, void* d_ws, size_t ws_size,
                              hipStream_t stream)
{
    (void)in_sizes; (void)n_in; (void)out_size;

    const float* x     = (const float*)d_in[0];
    const float* done  = (const float*)d_in[1];
    const float* h0    = (const float*)d_in[2];
    const float* c0in  = (const float*)d_in[3];
    const float* vW1   = (const float*)d_in[4];
    const float* vb1   = (const float*)d_in[5];
    const float* vW2   = (const float*)d_in[6];
    const float* vb2   = (const float*)d_in[7];
    const float* vW3   = (const float*)d_in[8];
    const float* vb3   = (const float*)d_in[9];
    const float* vWl   = (const float*)d_in[10];
    const float* vbl   = (const float*)d_in[11];
    const float* aW1   = (const float*)d_in[12];
    const float* ab1   = (const float*)d_in[13];
    const float* aW2   = (const float*)d_in[14];
    const float* ab2   = (const float*)d_in[15];
    const float* aW3   = (const float*)d_in[16];
    const float* ab3   = (const float*)d_in[17];
    const float* aWl   = (const float*)d_in[18];
    const float* abl   = (const float*)d_in[19];
    const float* vln_g = (const float*)d_in[20];
    const float* vln_b = (const float*)d_in[21];
    const float* aln_g = (const float*)d_in[22];
    const float* aln_b = (const float*)d_in[23];
    const float* att_vW = (const float*)d_in[24];
    const float* att_vb = (const float*)d_in[25];
    const float* att_aW = (const float*)d_in[26];
    const float* att_ab = (const float*)d_in[27];
    const float* att_sW = (const float*)d_in[28];
    const float* att_sb = (const float*)d_in[29];
    const float* attW  = (const float*)d_in[30];
    const float* attb  = (const float*)d_in[31];
    const float* Wih   = (const float*)d_in[32];
    const float* Whh   = (const float*)d_in[33];
    const float* bih   = (const float*)d_in[34];
    const float* bhh   = (const float*)d_in[35];

    float* out = (float*)d_out;
    float* vfaf = out + 262144;   // [2048][512] f32 (vf then af)

    // ---- adaptive batch chunk ----
    const size_t PERBATCH = 2ul * (12800 + 5184) * 2;   // c1 + c2, both towers
    const size_t PERSIST  =
          1024ul * 512 * 4       // gates
        + 2048ul * 512 * 4       // ych (both towers)
        + 1024ul * 640 * 2       // Acat
        + 512ul * 640 * 2        // Bcat
        + 2ul * 512 * 3136 * 2   // Wlb
        + 2ul * 2048 * 2         // Wp1
        + 2ul * 32768 * 2        // Wp2
        + 2ul * 36864 * 2        // Wp3
        + 36864ul * 2            // WTatt
        + 2ul * 1024 * 3136 * 2; // c3f (both towers)
    int NB = 64;
    const int cands[4] = {1024, 512, 256, 128};
    for (int i = 0; i < 4; ++i)
        if (PERSIST + (size_t)cands[i] * PERBATCH <= ws_size) { NB = cands[i]; break; }
    const int NC = 1024 / NB;

    // ---- workspace carve (gates then ych contiguous for pack_misc zeroing) --
    char* p = (char*)d_ws;
    float* gates = (float*)p; p += 1024ul * 512 * 4;
    float* ych   = (float*)p; p += 2048ul * 512 * 4;
    u16*   Acat  = (u16*)p;   p += 1024ul * 640 * 2;
    u16*   Bcat  = (u16*)p;   p += 512ul * 640 * 2;
    u16*   Wlb   = (u16*)p;   p += 2ul * 512 * 3136 * 2;
    u16*   Wp1   = (u16*)p;   p += 2ul * 2048 * 2;
    u16*   Wp2   = (u16*)p;   p += 2ul * 32768 * 2;
    u16*   Wp3   = (u16*)p;   p += 2ul * 36864 * 2;
    u16*   WTatt = (u16*)p;   p += 36864ul * 2;
    u16*   c3f   = (u16*)p;   p += 2ul * 1024 * 3136 * 2;
    u16*   c1    = (u16*)p;   p += 2ul * NB * 12800 * 2;
    u16*   c2    = (u16*)p;

    // 1) packs + zeros
    hipLaunchKernelGGL(pack_wl, dim3(1024), dim3(256), 0, stream, vWl, aWl, Wlb);
    hipLaunchKernelGGL(pack_misc, dim3(8128), dim3(256), 0, stream,
        vW1, aW1, vW2, aW2, vW3, aW3, att_vW, att_aW, att_sW, Wih, Whh,
        Wp1, Wp2, Wp3, WTatt, Bcat, gates);

    // 2) conv towers (wave-synchronous, fragment-order weights)
    for (int cch = 0; cch < NC; ++cch) {
        const int b0 = cch * NB;
        const int M1 = NB * 400, M2 = NB * 81, M3 = NB * 49;

        hipLaunchKernelGGL(conv1_mfma, dim3(M1 / 128, 2), dim3(256), 0, stream,
            x, (long)b0 * 14112, Wp1, vb1, ab1, c1, M1);

        hipLaunchKernelGGL((convW_mfma<32, 20, 20, 64, 4, 4, 2, 9, 9>),
            dim3((M2 + 127) / 128, 2), dim3(256), 0, stream,
            c1, (long)NB * 12800, Wp2, 32768, vb2, ab2,
            c2, (long)NB * 5184, M2);

        hipLaunchKernelGGL((convW_mfma<64, 9, 9, 64, 3, 3, 1, 7, 7>),
            dim3((M3 + 127) / 128, 2), dim3(256), 0, stream,
            c2, (long)NB * 5184, Wp3, 36864, vb3, ab3,
            c3f + (long)b0 * 3136, 1024l * 3136, M3);
    }

    // 3) tower linears as one M=2048 GEMM (B switches at row 1024), split-K 7
    hipLaunchKernelGGL(gemm_sk2, dim3(4, 16, 7), dim3(256), 0, stream,
        c3f, Wlb, Wlb + 512ul * 3136, ych, 2048, 1024, 512, 3136, 448);

    // 4) LN both towers -> vf/af f32 slots in d_out
    hipLaunchKernelGGL(ln_relu, dim3(2048), dim3(256), 0, stream,
        ych, vbl, abl, vln_g, aln_g, vln_b, aln_b, vfaf);

    // 5) attention gating -> Acat
    hipLaunchKernelGGL(attn_fuse, dim3(1024), dim3(256), 0, stream,
        vfaf, vfaf + 1024ul * 512, h0, done, WTatt,
        att_vb, att_ab, att_sb, attW, attb, Acat);

    // 6) gates GEMM (split-K 4)
    hipLaunchKernelGGL(gemm_sk2, dim3(4, 8, 4), dim3(256), 0, stream,
        Acat, Bcat, Bcat, gates, 1024, 1 << 30, 512, 640, 160);

    // 7) LSTM epilogue
    hipLaunchKernelGGL(lstm_fin, dim3(1024), dim3(128), 0, stream,
        gates, bih, bhh, c0in, done, out);
}

// Round 14
// 301.896 us; speedup vs baseline: 1.2501x; 1.0558x over previous
//
#include <hip/hip_runtime.h>

// ---------------------------------------------------------------------------
// AlignableCaslAgent forward.  Inputs f32, outputs f32 (verified rounds 4-13).
// Round 13: split-K GEMMs write per-slice PARTIAL buffers (plain stores, no
// atomics, no pre-zero); ln_relu+attn_fuse fused into ln_attn (sums the 7
// tower partials inline); lstm_fin sums the 4 gate partials inline.
// Conv path (wave-sync + fragment-order weights, 318us total) untouched.
// ---------------------------------------------------------------------------

typedef unsigned short u16;
typedef unsigned int u32;
typedef __attribute__((ext_vector_type(8))) short bf16x8;
typedef __attribute__((ext_vector_type(4))) float f32x4;

__device__ __forceinline__ float b2f(u16 u) {
    union { u32 i; float f; } v; v.i = ((u32)u) << 16; return v.f;
}
__device__ __forceinline__ u16 f2b(float f) {
    union { float f; u32 i; } v; v.f = f;
    u32 r = v.i + 0x7fffu + ((v.i >> 16) & 1u);
    return (u16)(r >> 16);
}
// wave-local LDS sync: fence + drain lgkmcnt only (vm loads stay in flight)
__device__ __forceinline__ void wave_lds_sync() {
    __builtin_amdgcn_wave_barrier();
    __builtin_amdgcn_s_waitcnt(0xC07F);
    __builtin_amdgcn_wave_barrier();
}

// ---------------------------------------------------------------------------
// conv1, wave-synchronous, fragment-order weights (unchanged round 12).
// ---------------------------------------------------------------------------
__global__ __launch_bounds__(256) void conv1_mfma(
    const float* __restrict__ x, long boff,
    const u16* __restrict__ Wp,
    const float* __restrict__ bias_v, const float* __restrict__ bias_a,
    u16* __restrict__ outp, int Mtot)
{
    __shared__ __attribute__((aligned(16))) u16 As[4 * 2304];

    const int tid = threadIdx.x;
    const int wave = tid >> 6, lane = tid & 63, quad = lane >> 4, l16 = lane & 15;
    const int t = blockIdx.y;
    const u16* Wpt = Wp + t * 2048;
    const float* bias = t ? bias_a : bias_v;
    u16* outt = outp + (long)t * Mtot * 32;

    const int mbase = blockIdx.x * 128 + wave * 32;
    const int rl = lane >> 1, h = lane & 1;
    int m = mbase + rl; if (m > Mtot - 1) m = Mtot - 1;
    const int bl = m / 400, p = m % 400;
    const int oy = p / 20, ox = p % 20;
    const float* F = x + boff + (long)bl * 14112 + t * 7056
                     + (long)(oy * 4) * 84 + ox * 4;

    {
        u16 tmp[32];
#pragma unroll
        for (int rr = 0; rr < 4; ++rr) {
            const int ky = h * 4 + rr;
            float4 v0 = *(const float4*)(F + ky * 84);
            float4 v1 = *(const float4*)(F + ky * 84 + 4);
            tmp[rr * 8 + 0] = f2b(v0.x); tmp[rr * 8 + 1] = f2b(v0.y);
            tmp[rr * 8 + 2] = f2b(v0.z); tmp[rr * 8 + 3] = f2b(v0.w);
            tmp[rr * 8 + 4] = f2b(v1.x); tmp[rr * 8 + 5] = f2b(v1.y);
            tmp[rr * 8 + 6] = f2b(v1.z); tmp[rr * 8 + 7] = f2b(v1.w);
        }
        u16* dst = As + wave * 2304 + rl * 72 + h * 32;
        const uint4* s = (const uint4*)tmp;
        *(uint4*)(dst)      = s[0];
        *(uint4*)(dst + 8)  = s[1];
        *(uint4*)(dst + 16) = s[2];
        *(uint4*)(dst + 24) = s[3];
    }
    wave_lds_sync();

    const u16* rb = As + wave * 2304;
    f32x4 acc[2][2];
#pragma unroll
    for (int mi = 0; mi < 2; ++mi)
#pragma unroll
        for (int ni = 0; ni < 2; ++ni)
            acc[mi][ni] = (f32x4){0.f, 0.f, 0.f, 0.f};

#pragma unroll
    for (int ks = 0; ks < 2; ++ks) {
        bf16x8 af[2], bf[2];
#pragma unroll
        for (int mi = 0; mi < 2; ++mi)
            af[mi] = *(const bf16x8*)(rb + (mi * 16 + l16) * 72 + ks * 32 + quad * 8);
#pragma unroll
        for (int ni = 0; ni < 2; ++ni)
            bf[ni] = *(const bf16x8*)(Wpt + ((ks * 2 + ni) * 64 + lane) * 8);
#pragma unroll
        for (int mi = 0; mi < 2; ++mi)
#pragma unroll
            for (int ni = 0; ni < 2; ++ni)
                acc[mi][ni] = __builtin_amdgcn_mfma_f32_16x16x32_bf16(
                    af[mi], bf[ni], acc[mi][ni], 0, 0, 0);
    }

#pragma unroll
    for (int mi = 0; mi < 2; ++mi)
#pragma unroll
        for (int ni = 0; ni < 2; ++ni) {
            const int col = ni * 16 + l16;
            const float bv = bias[col];
#pragma unroll
            for (int rr = 0; rr < 4; ++rr) {
                const int row = mbase + mi * 16 + quad * 4 + rr;
                if (row < Mtot)
                    outt[(long)row * 32 + col] = f2b(fmaxf(acc[mi][ni][rr] + bv, 0.f));
            }
        }
}

// ---------------------------------------------------------------------------
// Generic NHWC conv, wave-synchronous, fragment-order weights (unchanged).
// ---------------------------------------------------------------------------
template<int IC, int IH, int IW, int OC, int KH, int KW, int S, int OH, int OW>
__global__ __launch_bounds__(256) void convW_mfma(
    const u16* __restrict__ in, long inTs,
    const u16* __restrict__ Wp, int WpTs,
    const float* __restrict__ bias_v, const float* __restrict__ bias_a,
    u16* __restrict__ outp, long outTs, int Mtot)
{
    constexpr int OP  = OH * OW;
    constexpr int K   = KH * KW * IC;
    constexpr int NF  = OC / 16;
    constexpr int NCH = K / 64;

    __shared__ __attribute__((aligned(16))) u16 As[4 * 2 * 2304];

    const int tid = threadIdx.x;
    const int wave = tid >> 6, lane = tid & 63, quad = lane >> 4, l16 = lane & 15;
    const int t = blockIdx.y;
    const u16* int_ = in + (long)t * inTs;
    const u16* Wpt = Wp + (long)t * WpTs;
    const float* bias = t ? bias_a : bias_v;
    u16* outt = outp + (long)t * outTs;

    const int mbase = blockIdx.x * 128 + wave * 32;
    const int rl = lane >> 1, h = lane & 1;
    int m = mbase + rl; if (m > Mtot - 1) m = Mtot - 1;
    const int bl = m / OP, p = m % OP;
    const int oy = p / OW, ox = p % OW;
    const u16* abase = int_ + (((long)bl * IH + oy * S) * IW + ox * S) * IC + h * 32;

    u16* wbase = As + wave * 4608 + rl * 72 + h * 32;
    const u16* rbase = As + wave * 4608;

    f32x4 acc[2][NF];
#pragma unroll
    for (int mi = 0; mi < 2; ++mi)
#pragma unroll
        for (int ni = 0; ni < NF; ++ni)
            acc[mi][ni] = (f32x4){0.f, 0.f, 0.f, 0.f};

    uint4 pre0, pre1, pre2, pre3;
    {
        const uint4* s = (const uint4*)abase;
        pre0 = s[0]; pre1 = s[1]; pre2 = s[2]; pre3 = s[3];
    }

#pragma unroll
    for (int c = 0; c < NCH; ++c) {
        {
            u16* dst = wbase + (c & 1) * 2304;
            *(uint4*)(dst)      = pre0;
            *(uint4*)(dst + 8)  = pre1;
            *(uint4*)(dst + 16) = pre2;
            *(uint4*)(dst + 24) = pre3;
        }
        if (c + 1 < NCH) {
            const int k0 = (c + 1) * 64;
            const int pos = k0 / IC;
            const int ky = pos / KW, kx = pos - ky * KW;
            const uint4* s = (const uint4*)(abase + ((long)ky * IW + kx) * IC);
            pre0 = s[0]; pre1 = s[1]; pre2 = s[2]; pre3 = s[3];
        }
        wave_lds_sync();

        const u16* rb = rbase + (c & 1) * 2304;
#pragma unroll
        for (int ks = 0; ks < 2; ++ks) {
            bf16x8 af[2], bf[NF];
#pragma unroll
            for (int mi = 0; mi < 2; ++mi)
                af[mi] = *(const bf16x8*)(rb + (mi * 16 + l16) * 72 + ks * 32 + quad * 8);
#pragma unroll
            for (int ni = 0; ni < NF; ++ni)
                bf[ni] = *(const bf16x8*)(Wpt + (((c * 2 + ks) * NF + ni) * 64 + lane) * 8);
#pragma unroll
            for (int mi = 0; mi < 2; ++mi)
#pragma unroll
                for (int ni = 0; ni < NF; ++ni)
                    acc[mi][ni] = __builtin_amdgcn_mfma_f32_16x16x32_bf16(
                        af[mi], bf[ni], acc[mi][ni], 0, 0, 0);
        }
        __builtin_amdgcn_wave_barrier();
    }

#pragma unroll
    for (int mi = 0; mi < 2; ++mi)
#pragma unroll
        for (int ni = 0; ni < NF; ++ni) {
            const int col = ni * 16 + l16;
            const float bv = bias[col];
#pragma unroll
            for (int rr = 0; rr < 4; ++rr) {
                const int row = mbase + mi * 16 + quad * 4 + rr;
                if (row < Mtot)
                    outt[(long)row * OC + col] = f2b(fmaxf(acc[ni < NF ? mi : mi][ni][rr] + bv, 0.f));
            }
        }
}

// ---------------------------------------------------------------------------
// Split-K MFMA GEMM writing PARTIAL buffers: Cp[z][M][N] = A*B^T over slice z.
// Plain stores - no atomics, no pre-zero.  Per-M-tile B select kept.
// ---------------------------------------------------------------------------
#define LDSP 40
__global__ __launch_bounds__(256) void gemm_skp(
    const u16* __restrict__ A, const u16* __restrict__ B0,
    const u16* __restrict__ B1,
    float* __restrict__ Cp, int M, int Mhalf, int N, int K, int Kc)
{
    __shared__ __attribute__((aligned(16))) u16 As[128 * LDSP];
    __shared__ __attribute__((aligned(16))) u16 Bs[128 * LDSP];

    const int tid  = threadIdx.x;
    const int wave = tid >> 6, lane = tid & 63;
    const int quad = lane >> 4, l16 = lane & 15;
    const int m0 = blockIdx.y * 128, n0 = blockIdx.x * 128;
    const u16* B = (m0 < Mhalf) ? B0 : B1;
    const int wm = (wave >> 1) * 64, wn = (wave & 1) * 64;
    const int kfrom = blockIdx.z * Kc;
    int kto = kfrom + Kc; if (kto > K) kto = K;
    float* C = Cp + (long)blockIdx.z * M * N;

    f32x4 acc[4][4];
#pragma unroll
    for (int mi = 0; mi < 4; ++mi)
#pragma unroll
        for (int ni = 0; ni < 4; ++ni)
            acc[mi][ni] = (f32x4){0.f, 0.f, 0.f, 0.f};

    for (int k0 = kfrom; k0 < kto; k0 += 32) {
        __syncthreads();
#pragma unroll
        for (int pass = 0; pass < 2; ++pass) {
            int idx = tid + pass * 256;
            int r = idx >> 2, seg = idx & 3;
            int gr = m0 + r; if (gr > M - 1) gr = M - 1;
            uint4 va = *(const uint4*)(A + (long)gr * K + k0 + seg * 8);
            *(uint4*)(As + r * LDSP + seg * 8) = va;
            uint4 vb = *(const uint4*)(B + (long)(n0 + r) * K + k0 + seg * 8);
            *(uint4*)(Bs + r * LDSP + seg * 8) = vb;
        }
        __syncthreads();

        bf16x8 af[4], bfr[4];
#pragma unroll
        for (int mi = 0; mi < 4; ++mi)
            af[mi] = *(const bf16x8*)(As + (wm + mi * 16 + l16) * LDSP + quad * 8);
#pragma unroll
        for (int ni = 0; ni < 4; ++ni)
            bfr[ni] = *(const bf16x8*)(Bs + (wn + ni * 16 + l16) * LDSP + quad * 8);
#pragma unroll
        for (int mi = 0; mi < 4; ++mi)
#pragma unroll
            for (int ni = 0; ni < 4; ++ni)
                acc[mi][ni] = __builtin_amdgcn_mfma_f32_16x16x32_bf16(
                    af[mi], bfr[ni], acc[mi][ni], 0, 0, 0);
    }

#pragma unroll
    for (int mi = 0; mi < 4; ++mi)
#pragma unroll
        for (int ni = 0; ni < 4; ++ni) {
            int col = n0 + wn + ni * 16 + l16;
#pragma unroll
            for (int rr = 0; rr < 4; ++rr) {
                int row = m0 + wm + mi * 16 + quad * 4 + rr;
                if (row < M) C[(long)row * N + col] = acc[mi][ni][rr];
            }
        }
}

// ---------------------------------------------------------------------------
// Wl [512][3136] (k = oc*49+p) -> [n][p*64+oc] bf16 via LDS row transpose.
// ---------------------------------------------------------------------------
__global__ __launch_bounds__(256) void pack_wl(
    const float* __restrict__ vWl, const float* __restrict__ aWl,
    u16* __restrict__ dst)
{
    __shared__ float row[3136];
    const int bid = blockIdx.x, tid = threadIdx.x;
    const int n = bid & 511;
    const float* src = (bid < 512) ? vWl : aWl;
    for (int i = tid; i < 3136; i += 256)
        row[i] = src[(long)n * 3136 + i];
    __syncthreads();
    u16* d = dst + (long)bid * 3136;
    for (int i = tid; i < 3136; i += 256) {
        int p = i >> 6, oc = i & 63;
        d[i] = f2b(row[oc * 49 + p]);
    }
}

// ---------------------------------------------------------------------------
// All small weight packs in ONE kernel (zeroing removed - no longer needed).
// Conv weights packed in MFMA-fragment order.  Grid = 1984 blocks.
// ---------------------------------------------------------------------------
__global__ __launch_bounds__(256) void pack_misc(
    const float* __restrict__ vW1, const float* __restrict__ aW1,
    const float* __restrict__ vW2, const float* __restrict__ aW2,
    const float* __restrict__ vW3, const float* __restrict__ aW3,
    const float* __restrict__ avW, const float* __restrict__ aaW,
    const float* __restrict__ asW,
    const float* __restrict__ Wih, const float* __restrict__ Whh,
    u16* __restrict__ Wp1, u16* __restrict__ Wp2, u16* __restrict__ Wp3,
    u16* __restrict__ WTatt, u16* __restrict__ Bcat)
{
    const int idx = blockIdx.x * 256 + threadIdx.x;
    if (idx < 4096) {                // Wp1f: [t][ks*2+ni][lane][8], K=64, NF=2
        const float* s = (idx < 2048) ? vW1 : aW1;
        int j0 = idx & 2047;
        int jj = j0 & 7, lane = (j0 >> 3) & 63, rest = j0 >> 9;
        int ni = rest & 1, ks = rest >> 1;
        int oc = ni * 16 + (lane & 15);
        int k  = ks * 32 + (lane >> 4) * 8 + jj;
        Wp1[idx] = f2b(s[oc * 64 + k]);
    } else if (idx < 69632) {        // Wp2f: K=512, IC=32, KW=4, NF=4
        int i = idx - 4096;
        const float* s = (i < 32768) ? vW2 : aW2;
        int j0 = i & 32767;
        int jj = j0 & 7, lane = (j0 >> 3) & 63, rest = j0 >> 9;
        int ni = rest & 3, rest2 = rest >> 2;
        int ks = rest2 & 1, c = rest2 >> 1;
        int oc = ni * 16 + (lane & 15);
        int k  = c * 64 + ks * 32 + (lane >> 4) * 8 + jj;
        int pos = k >> 5, ic = k & 31;
        int ky = pos >> 2, kx = pos & 3;
        Wp2[i] = f2b(s[((oc * 32 + ic) * 4 + ky) * 4 + kx]);
    } else if (idx < 143360) {       // Wp3f: K=576, IC=64, KW=3, NF=4
        int i = idx - 69632;
        const float* s = (i < 36864) ? vW3 : aW3;
        int j0 = i % 36864;
        int jj = j0 & 7, lane = (j0 >> 3) & 63, rest = j0 >> 9;
        int ni = rest & 3, rest2 = rest >> 2;
        int ks = rest2 & 1, c = rest2 >> 1;
        int oc = ni * 16 + (lane & 15);
        int k  = c * 64 + ks * 32 + (lane >> 4) * 8 + jj;
        int pos = k >> 6, ic = k & 63;
        int ky = pos / 3, kx = pos % 3;
        Wp3[i] = f2b(s[((oc * 64 + ic) * 3 + ky) * 3 + kx]);
    } else if (idx < 180224) {       // WTatt: [1152][32]
        int i = idx - 143360;
        int k = i >> 5, j = i & 31;
        float v = (k < 512) ? avW[(long)j * 512 + k]
                : (k < 1024) ? aaW[(long)j * 512 + (k - 512)]
                : asW[(long)j * 128 + (k - 1024)];
        WTatt[i] = f2b(v);
    } else if (idx < 507904) {       // Bcat: [512][640]
        int i = idx - 180224;
        int n = i / 640, k = i % 640;
        Bcat[i] = f2b((k < 512) ? Wih[(long)n * 512 + k]
                                : Whh[(long)n * 128 + (k - 512)]);
    }
}

// ---------------------------------------------------------------------------
// FUSED: partial-sum reduce (7 slices) + bias + ReLU + LayerNorm for BOTH
// towers + attention gating.  Block b handles ych rows b (video) and
// 1024+b (audio); writes vf/af f32 to d_out and Acat bf16.
// ---------------------------------------------------------------------------
__global__ __launch_bounds__(256) void ln_attn(
    const float* __restrict__ ychp,       // [7][2048][512]
    const float* __restrict__ bl_v, const float* __restrict__ bl_a,
    const float* __restrict__ g_v,  const float* __restrict__ g_a,
    const float* __restrict__ be_v, const float* __restrict__ be_a,
    const float* __restrict__ h0,   const float* __restrict__ done,
    const u16* __restrict__ WT,
    const float* __restrict__ avb, const float* __restrict__ aab,
    const float* __restrict__ asb,
    const float* __restrict__ attW, const float* __restrict__ attb,
    float* __restrict__ vf_out, float* __restrict__ af_out,
    u16* __restrict__ Acat)
{
    __shared__ float vs[512], afs[512], hs[128], red[256], part[8][32], act[32], wsm[2];
    __shared__ float mean_s, inv_s;
    const int b = blockIdx.x, tid = threadIdx.x;

    if (tid < 128) hs[tid] = h0[b * 128 + tid];

#pragma unroll
    for (int tw = 0; tw < 2; ++tw) {
        const long row = tw ? (1024 + b) : b;
        const float* bias = tw ? bl_a : bl_v;
        const float* g    = tw ? g_a  : g_v;
        const float* be   = tw ? be_a : be_v;
        float* fo   = tw ? af_out : vf_out;
        float* dst  = tw ? afs : vs;

        float s0 = bias[tid], s1 = bias[tid + 256];
#pragma unroll
        for (int z = 0; z < 7; ++z) {
            const float* yr = ychp + (long)z * 1048576 + row * 512;
            s0 += yr[tid];
            s1 += yr[tid + 256];
        }
        float v0 = fmaxf(s0, 0.f), v1 = fmaxf(s1, 0.f);

        __syncthreads();                 // red[] free from previous use
        red[tid] = v0 + v1;
        __syncthreads();
        for (int s = 128; s > 0; s >>= 1) { if (tid < s) red[tid] += red[tid + s]; __syncthreads(); }
        if (tid == 0) mean_s = red[0] * (1.f / 512.f);
        __syncthreads();
        float mean = mean_s;
        float d0 = v0 - mean, d1 = v1 - mean;
        red[tid] = d0 * d0 + d1 * d1;
        __syncthreads();
        for (int s = 128; s > 0; s >>= 1) { if (tid < s) red[tid] += red[tid + s]; __syncthreads(); }
        if (tid == 0) inv_s = rsqrtf(red[0] * (1.f / 512.f) + 1e-5f);
        __syncthreads();
        float inv = inv_s;

        float o0 = d0 * inv * g[tid]       + be[tid];
        float o1 = d1 * inv * g[tid + 256] + be[tid + 256];
        dst[tid] = o0; dst[tid + 256] = o1;
        fo[(long)b * 512 + tid]       = o0;
        fo[(long)b * 512 + tid + 256] = o1;
    }
    __syncthreads();

    {
        const int j = tid & 31, g = tid >> 5;
        float a = 0.f;
#pragma unroll 8
        for (int k = g * 64; k < g * 64 + 64; ++k)
            a += vs[k] * b2f(WT[k * 32 + j]);
#pragma unroll 8
        for (int k = g * 64; k < g * 64 + 64; ++k)
            a += afs[k] * b2f(WT[(512 + k) * 32 + j]);
#pragma unroll 8
        for (int k = g * 16; k < g * 16 + 16; ++k)
            a += hs[k] * b2f(WT[(1024 + k) * 32 + j]);
        part[g][j] = a;
    }
    __syncthreads();
    if (tid < 32) {
        float a = avb[tid] + aab[tid] + asb[tid];
#pragma unroll
        for (int g2 = 0; g2 < 8; ++g2) a += part[g2][tid];
        act[tid] = tanhf(a);
    }
    __syncthreads();
    if (tid == 0) {
        float l0 = attb[0], l1 = attb[1];
        for (int j = 0; j < 32; ++j) {
            l0 += act[j] * attW[j];
            l1 += act[j] * attW[32 + j];
        }
        float mx = fmaxf(l0, l1);
        float e0 = expf(l0 - mx), e1 = expf(l1 - mx);
        float s = e0 + e1;
        wsm[0] = e0 / s; wsm[1] = e1 / s;
    }
    __syncthreads();
    const float w0 = wsm[0], w1 = wsm[1];
    const float m = 1.f - done[b];
    for (int i = tid; i < 512; i += 256)
        Acat[(long)b * 640 + i] = f2b(w0 * vs[i] + w1 * afs[i]);
    if (tid < 128)
        Acat[(long)b * 640 + 512 + tid] = f2b(m * hs[tid]);
}

// ---------------------------------------------------------------------------
// LSTM pointwise epilogue; sums the 4 gate partial slices inline.
// ---------------------------------------------------------------------------
__global__ __launch_bounds__(128) void lstm_fin(
    const float* __restrict__ gatesp,     // [4][1024][512]
    const float* __restrict__ bih, const float* __restrict__ bhh,
    const float* __restrict__ c0, const float* __restrict__ done,
    float* __restrict__ out)
{
    const int b = blockIdx.x, j = threadIdx.x;
    float gi = bih[j]       + bhh[j];
    float gf = bih[128 + j] + bhh[128 + j];
    float gg = bih[256 + j] + bhh[256 + j];
    float go = bih[384 + j] + bhh[384 + j];
#pragma unroll
    for (int z = 0; z < 4; ++z) {
        const float* G = gatesp + (long)z * 524288 + (long)b * 512;
        gi += G[j]; gf += G[128 + j]; gg += G[256 + j]; go += G[384 + j];
    }
    float m  = 1.f - done[b];
    float c  = m * c0[b * 128 + j];
    float si = 1.f / (1.f + expf(-gi));
    float sf = 1.f / (1.f + expf(-gf));
    float so = 1.f / (1.f + expf(-go));
    float cn = sf * c + si * tanhf(gg);
    float hn = so * tanhf(cn);
    out[b * 128 + j]          = hn;
    out[131072 + b * 128 + j] = cn;
}

// ---------------------------------------------------------------------------
extern "C" void kernel_launch(void* const* d_in, const int* in_sizes, int n_in,
                              void* d_out, int out_size, void* d_ws, size_t ws_size,
                              hipStream_t stream)
{
    (void)in_sizes; (void)n_in; (void)out_size;

    const float* x     = (const float*)d_in[0];
    const float* done  = (const float*)d_in[1];
    const float* h0    = (const float*)d_in[2];
    const float* c0in  = (const float*)d_in[3];
    const float* vW1   = (const float*)d_in[4];
    const float* vb1   = (const float*)d_in[5];
    const float* vW2   = (const float*)d_in[6];
    const float* vb2   = (const float*)d_in[7];
    const float* vW3   = (const float*)d_in[8];
    const float* vb3   = (const float*)d_in[9];
    const float* vWl   = (const float*)d_in[10];
    const float* vbl   = (const float*)d_in[11];
    const float* aW1   = (const float*)d_in[12];
    const float* ab1   = (const float*)d_in[13];
    const float* aW2   = (const float*)d_in[14];
    const float* ab2   = (const float*)d_in[15];
    const float* aW3   = (const float*)d_in[16];
    const float* ab3   = (const float*)d_in[17];
    const float* aWl   = (const float*)d_in[18];
    const float* abl   = (const float*)d_in[19];
    const float* vln_g = (const float*)d_in[20];
    const float* vln_b = (const float*)d_in[21];
    const float* aln_g = (const float*)d_in[22];
    const float* aln_b = (const float*)d_in[23];
    const float* att_vW = (const float*)d_in[24];
    const float* att_vb = (const float*)d_in[25];
    const float* att_aW = (const float*)d_in[26];
    const float* att_ab = (const float*)d_in[27];
    const float* att_sW = (const float*)d_in[28];
    const float* att_sb = (const float*)d_in[29];
    const float* attW  = (const float*)d_in[30];
    const float* attb  = (const float*)d_in[31];
    const float* Wih   = (const float*)d_in[32];
    const float* Whh   = (const float*)d_in[33];
    const float* bih   = (const float*)d_in[34];
    const float* bhh   = (const float*)d_in[35];

    float* out = (float*)d_out;
    float* vf_out = out + 262144;
    float* af_out = out + 786432;

    // ---- adaptive batch chunk ----
    const size_t PERBATCH = 2ul * (12800 + 5184) * 2;   // c1 + c2, both towers
    const size_t PERSIST  =
          4ul * 1024 * 512 * 4       // gatesp (4 slices)
        + 7ul * 2048 * 512 * 4       // ychp (7 slices)
        + 1024ul * 640 * 2           // Acat
        + 512ul * 640 * 2            // Bcat
        + 2ul * 512 * 3136 * 2       // Wlb
        + 2ul * 2048 * 2             // Wp1
        + 2ul * 32768 * 2            // Wp2
        + 2ul * 36864 * 2            // Wp3
        + 36864ul * 2                // WTatt
        + 2ul * 1024 * 3136 * 2;     // c3f (both towers)
    int NB = 64;
    const int cands[4] = {1024, 512, 256, 128};
    for (int i = 0; i < 4; ++i)
        if (PERSIST + (size_t)cands[i] * PERBATCH <= ws_size) { NB = cands[i]; break; }
    const int NC = 1024 / NB;

    // ---- workspace carve ----
    char* p = (char*)d_ws;
    float* gatesp = (float*)p; p += 4ul * 1024 * 512 * 4;
    float* ychp   = (float*)p; p += 7ul * 2048 * 512 * 4;
    u16*   Acat   = (u16*)p;   p += 1024ul * 640 * 2;
    u16*   Bcat   = (u16*)p;   p += 512ul * 640 * 2;
    u16*   Wlb    = (u16*)p;   p += 2ul * 512 * 3136 * 2;
    u16*   Wp1    = (u16*)p;   p += 2ul * 2048 * 2;
    u16*   Wp2    = (u16*)p;   p += 2ul * 32768 * 2;
    u16*   Wp3    = (u16*)p;   p += 2ul * 36864 * 2;
    u16*   WTatt  = (u16*)p;   p += 36864ul * 2;
    u16*   c3f    = (u16*)p;   p += 2ul * 1024 * 3136 * 2;
    u16*   c1     = (u16*)p;   p += 2ul * NB * 12800 * 2;
    u16*   c2     = (u16*)p;

    // 1) packs
    hipLaunchKernelGGL(pack_wl, dim3(1024), dim3(256), 0, stream, vWl, aWl, Wlb);
    hipLaunchKernelGGL(pack_misc, dim3(1984), dim3(256), 0, stream,
        vW1, aW1, vW2, aW2, vW3, aW3, att_vW, att_aW, att_sW, Wih, Whh,
        Wp1, Wp2, Wp3, WTatt, Bcat);

    // 2) conv towers (wave-synchronous, fragment-order weights)
    for (int cch = 0; cch < NC; ++cch) {
        const int b0 = cch * NB;
        const int M1 = NB * 400, M2 = NB * 81, M3 = NB * 49;

        hipLaunchKernelGGL(conv1_mfma, dim3(M1 / 128, 2), dim3(256), 0, stream,
            x, (long)b0 * 14112, Wp1, vb1, ab1, c1, M1);

        hipLaunchKernelGGL((convW_mfma<32, 20, 20, 64, 4, 4, 2, 9, 9>),
            dim3((M2 + 127) / 128, 2), dim3(256), 0, stream,
            c1, (long)NB * 12800, Wp2, 32768, vb2, ab2,
            c2, (long)NB * 5184, M2);

        hipLaunchKernelGGL((convW_mfma<64, 9, 9, 64, 3, 3, 1, 7, 7>),
            dim3((M3 + 127) / 128, 2), dim3(256), 0, stream,
            c2, (long)NB * 5184, Wp3, 36864, vb3, ab3,
            c3f + (long)b0 * 3136, 1024l * 3136, M3);
    }

    // 3) tower linears: M=2048 GEMM, split-K 7 -> partial slices (no atomics)
    hipLaunchKernelGGL(gemm_skp, dim3(4, 16, 7), dim3(256), 0, stream,
        c3f, Wlb, Wlb + 512ul * 3136, ychp, 2048, 1024, 512, 3136, 448);

    // 4) fused partial-reduce + LN (both towers) + attention -> vf/af + Acat
    hipLaunchKernelGGL(ln_attn, dim3(1024), dim3(256), 0, stream,
        ychp, vbl, abl, vln_g, aln_g, vln_b, aln_b, h0, done, WTatt,
        att_vb, att_ab, att_sb, attW, attb, vf_out, af_out, Acat);

    // 5) gates GEMM: split-K 4 -> partial slices
    hipLaunchKernelGGL(gemm_skp, dim3(4, 8, 4), dim3(256), 0, stream,
        Acat, Bcat, Bcat, gatesp, 1024, 1 << 30, 512, 640, 160);

    // 6) LSTM epilogue (sums 4 partials)
    hipLaunchKernelGGL(lstm_fin, dim3(1024), dim3(128), 0, stream,
        gatesp, bih, bhh, c0in, done, out);
}